// Round 1
// 113.361 us; speedup vs baseline: 1.2514x; 1.2514x over previous
//
#include <hip/hip_runtime.h>
#include <math.h>

#define B_ 32
#define D_ 16
#define T_ 1024
#define P_ 64
#define L_ 32
#define KB 524288.0f       // 2^19 bias: prefmin(e) = KB - prefmax(KB - e)

typedef short short8 __attribute__((ext_vector_type(8)));
typedef float f32x4 __attribute__((ext_vector_type(4)));
typedef unsigned short ushort_t;

// ---- DPP helpers -----------------------------------------------------------
template<int CTRL, int ROW_MASK, bool BC>
__device__ __forceinline__ float dpp_mov(float old_, float src) {
  int o = __builtin_bit_cast(int, old_);
  int s = __builtin_bit_cast(int, src);
  int r = __builtin_amdgcn_update_dpp(o, s, CTRL, ROW_MASK, 0xf, BC);
  return __builtin_bit_cast(float, r);
}

// Inclusive prefix-sum over each 32-lane half (0-fill -> fused v_add_f32_dpp).
__device__ __forceinline__ float scan_sum32(float v) {
  v += dpp_mov<0x111, 0xf, true>(0.f, v);   // row_shr:1
  v += dpp_mov<0x112, 0xf, true>(0.f, v);   // row_shr:2
  v += dpp_mov<0x114, 0xf, true>(0.f, v);   // row_shr:4
  v += dpp_mov<0x118, 0xf, true>(0.f, v);   // row_shr:8
  v += dpp_mov<0x142, 0xa, false>(0.f, v);  // row_bcast15 -> rows 1,3
  return v;
}

// Inclusive prefix-MAX over each 32-lane half.
// Hand-fused v_max_f32_dpp: GCNDPPCombine can't fuse update_dpp+max (0 is not
// the max identity), so the builtin path costs 15 VALU ops; this is 5.
// Skip-write OOB (bound_ctrl=0) keeps the lane's own running max -> exactly
// the prefix-max identity, valid for any sign. row_bcast:15 with row_mask 0xa
// leaves rows 0,2 untouched (keep own value) as before.
// s_nop 1 between steps: mandatory 2 wait states for VALU->DPP-src hazard
// (inline asm contents are invisible to the compiler's hazard recognizer).
__device__ __forceinline__ float scan_max32(float v) {
  asm("s_nop 1\n\t"
      "v_max_f32_dpp %0, %0, %0 row_shr:1 row_mask:0xf bank_mask:0xf\n\t"
      "s_nop 1\n\t"
      "v_max_f32_dpp %0, %0, %0 row_shr:2 row_mask:0xf bank_mask:0xf\n\t"
      "s_nop 1\n\t"
      "v_max_f32_dpp %0, %0, %0 row_shr:4 row_mask:0xf bank_mask:0xf\n\t"
      "s_nop 1\n\t"
      "v_max_f32_dpp %0, %0, %0 row_shr:8 row_mask:0xf bank_mask:0xf\n\t"
      "s_nop 1\n\t"
      "v_max_f32_dpp %0, %0, %0 row_bcast:15 row_mask:0xa bank_mask:0xf"
      : "+v"(v));
  return v;
}

__device__ __forceinline__ ushort_t f2bf(float f) {   // fp32 -> bf16 RNE
  unsigned u = __builtin_bit_cast(unsigned, f);
  return (ushort_t)((u + 0x7FFFu + ((u >> 16) & 1u)) >> 16);
}
__device__ __forceinline__ float bf2f(ushort_t h) {
  unsigned u = ((unsigned)h) << 16;
  return __builtin_bit_cast(float, u);
}

// ---- prep_x: xA[b][t][32 bf16] --------------------------------------------
// [0..15]=x, [16..17]=1, [18..19]=x2hi/lo, [20..31]=0   (byte-identical)
__global__ void prep_x(const float* __restrict__ x, ushort_t* __restrict__ xA) {
  int gid = blockIdx.x * blockDim.x + threadIdx.x;
  if (gid >= B_ * T_) return;
  int b = gid >> 10, t = gid & 1023;
  float x2 = 0.f;
  ushort_t o[32];
#pragma unroll
  for (int d = 0; d < 16; ++d) {
    float v = x[((b * 16 + d) << 10) + t];   // coalesced over t
    x2 = fmaf(v, v, x2);
    o[d] = f2bf(v);
  }
  o[16] = 0x3F80; o[17] = 0x3F80;            // bf16(1.0)
  ushort_t hi = f2bf(x2);
  o[18] = hi;
  o[19] = f2bf(x2 - bf2f(hi));               // hi/lo split
#pragma unroll
  for (int d = 20; d < 32; ++d) o[d] = 0;
  uint4* dst = (uint4*)(xA + (size_t)gid * 32);
#pragma unroll
  for (int q = 0; q < 4; ++q) {
    const ushort_t* s = o + q * 8;
    uint4 u;
    u.x = (unsigned)s[0] | ((unsigned)s[1] << 16);
    u.y = (unsigned)s[2] | ((unsigned)s[3] << 16);
    u.z = (unsigned)s[4] | ((unsigned)s[5] << 16);
    u.w = (unsigned)s[6] | ((unsigned)s[7] << 16);
    dst[q] = u;
  }
}

// ---- prep_patt: PREFIX-ACCUMULATED B fragments via DPP scans ---------------
// (unchanged)
__global__ __launch_bounds__(64) void prep_patt(const float* __restrict__ patts,
                                                ushort_t* __restrict__ pB) {
  __shared__ float Ls[16 * 33];    // [d][m], stride 33 (conflict-free gathers)
  __shared__ float Lh[64];         // per-half p2 partial sums
  __shared__ float LP2[32];        // prefix of p2 totals

  const int p = blockIdx.x;
  const int l = threadIdx.x;
  const int half = l >> 5;
  const int m = l & 31;

  float p2acc = 0.f;
#pragma unroll
  for (int dd = 0; dd < 16; dd += 2) {
    int d = dd + half;                       // half 0: even d, half 1: odd d
    float v = patts[((p * 16 + d) << 5) + m];
    p2acc = fmaf(v, v, p2acc);
    Ls[d * 33 + m] = scan_sum32(v);          // prefix over m (per half)
  }
  Lh[l] = p2acc;
  __syncthreads();
  {
    float tot = Lh[m] + Lh[32 + m];          // both halves compute (redundant)
    float pref = scan_sum32(tot);
    if (half == 0) LP2[m] = pref;
  }
  __syncthreads();

  // output: 2 iblks x 64 lanes; lane l -> n=l&15, q=l>>4, i=iblk*16+n
  const int n = l & 15, q = l >> 4;
#pragma unroll
  for (int iblk = 0; iblk < 2; ++iblk) {
    const int i = iblk * 16 + n;
    ushort_t o[8];
    if (q < 2) {
#pragma unroll
      for (int e = 0; e < 8; ++e)
        o[e] = f2bf(-2.f * Ls[(q * 8 + e) * 33 + i]);
    } else if (q == 2) {
      float P2 = LP2[i];
      ushort_t hi = f2bf(P2);
      o[0] = hi; o[1] = f2bf(P2 - bf2f(hi));
      o[2] = f2bf((float)(i + 1)); o[3] = o[2];
      o[4] = o[5] = o[6] = o[7] = 0;
    } else {
#pragma unroll
      for (int e = 0; e < 8; ++e) o[e] = 0;
    }
    uint4 u;
    u.x = (unsigned)o[0] | ((unsigned)o[1] << 16);
    u.y = (unsigned)o[2] | ((unsigned)o[3] << 16);
    u.z = (unsigned)o[4] | ((unsigned)o[5] << 16);
    u.w = (unsigned)o[6] | ((unsigned)o[7] << 16);
    ((uint4*)pB)[(p * 2 + iblk) * 64 + l] = u;
  }
}

// ---- main kernel -----------------------------------------------------------
// R15 changes vs 141.4us version (bitwise-identical arithmetic):
//  * scan_max32 hand-fused to 5x v_max_f32_dpp (was 15 VALU ops).
//  * Sx (= S[i-1][j]) now read from LDS one row up (pad row of 0.0f per
//    pattern block) instead of per-column wave_shr+cndmask: 4 extra
//    ds_read_b128/tile replace 32 VALU ops/tile. LDS pipe was ~16% busy.
//  * t1 = KB + Sx and spk = KB + S precomputed off the dcur critical chain.
//  * stores batched once per tile (one exec-mask region per tile, keeps
//    EXEC-write -> DPP hazard far away from the asm scan).
// Layout: per wave 2640 floats: 2 buf x { [pad 20][pat0 32x20] [pad 20][pat1 32x20] }.
__global__ __launch_bounds__(256, 3) void dtw_kernel(
    const ushort_t* __restrict__ xA,    // [B][T][32 bf16]
    const ushort_t* __restrict__ pBg,   // [P][2][64][8 bf16]
    const float* __restrict__ wp,
    float* __restrict__ out)            // [B][P][T]
{
  __shared__ float lds[4 * 2640];   // 4 waves * 2 buf * 2*(pad+32x20) floats

  const int tid = threadIdx.x;
  const int l   = tid & 63;
  const int wid = tid >> 6;
  const int li  = l & 31;
  const int g   = l >> 5;
  const int q4  = l >> 4;
  const unsigned bx = blockIdx.x;
  const int ch   = bx % 3u;               // chunk: tiles [16ch, 16ch+32)
  const int rest = bx / 3u;
  const int b     = rest >> 3;
  const int pbase = (rest & 7) << 3;
  const int pA  = pbase + (wid << 1);
  const float w = wp[0];
  const float nw = -w;
  const bool l0c = (li == 0), l31 = (li == 31);

  const int t0    = ch << 4;              // 0 / 16 / 32
  const int warmT = ch ? 16 : 0;          // local tiles < warmT: no store

  // B fragments (loop-invariant MFMA operands -> register-resident)
  const short8* pBs = (const short8*)pBg;
  short8 B00 = pBs[((pA    ) * 2 + 0) * 64 + l];
  short8 B01 = pBs[((pA    ) * 2 + 1) * 64 + l];
  short8 B10 = pBs[((pA + 1) * 2 + 0) * 64 + l];
  short8 B11 = pBs[((pA + 1) * 2 + 1) * 64 + l];

  const short8* xAs = (const short8*)xA + ((size_t)b << 12);

  short8 Aa;
  auto loadA = [&](int t) {   // t local; global tile = t0 + t
    Aa = xAs[((((t0 + t) << 4) + (l & 15)) << 2) + q4];
  };

  // write base: +20 skips the pad row; pattern blocks at 0 / 660 within a buf
  float* ldsW = lds + wid * 2640 + 20 + (l & 15) * 20 + q4 * 4;
  const float* ldsR  = lds + wid * 2640 + 20 + g * 660 + li * 20;  // S row li
  const float* ldsRx = ldsR - 20;                                  // row li-1 (li==0 -> pad)

  // zero the pad rows once (Sx for i==0 reads these; never overwritten)
  {
    float* pb = lds + wid * 2640;
    if (l < 20) {
      pb[l] = 0.f; pb[660 + l] = 0.f; pb[1320 + l] = 0.f; pb[1980 + l] = 0.f;
    }
  }
  __syncthreads();

  auto fill = [&](int bufsel) {
    f32x4 z = {0.f, 0.f, 0.f, 0.f};
    float* wb = ldsW + bufsel * 1320;
    f32x4 d0 = __builtin_amdgcn_mfma_f32_16x16x32_bf16(Aa, B00, z, 0, 0, 0);
    f32x4 d1 = __builtin_amdgcn_mfma_f32_16x16x32_bf16(Aa, B01, z, 0, 0, 0);
    f32x4 d2 = __builtin_amdgcn_mfma_f32_16x16x32_bf16(Aa, B10, z, 0, 0, 0);
    f32x4 d3 = __builtin_amdgcn_mfma_f32_16x16x32_bf16(Aa, B11, z, 0, 0, 0);
    *(f32x4*)(wb + 0)   = d0;      // pat0, i 0..15   ([i][j] stride 20)
    *(f32x4*)(wb + 320) = d1;      // pat0, i 16..31
    *(f32x4*)(wb + 660) = d2;      // pat1, i 0..15
    *(f32x4*)(wb + 980) = d3;      // pat1, i 16..31
  };

  float* orow = out + (((size_t)(b * P_ + pA + g)) << 10) + (t0 << 4);
  float dcur = 0.f;

  auto DP = [&](int bufsel, bool first, bool store, float* op) {
    const float* rb = ldsR  + bufsel * 1320;
    const float* rx = ldsRx + bufsel * 1320;
    f32x4 s0 = *(const f32x4*)(rb + 0);     // S rows (own lane)
    f32x4 x0 = *(const f32x4*)(rx + 0);     // S rows shifted up by 1 (= Sx)
    f32x4 s1 = *(const f32x4*)(rb + 4);
    f32x4 x1 = *(const f32x4*)(rx + 4);
    f32x4 s2 = *(const f32x4*)(rb + 8);
    f32x4 x2 = *(const f32x4*)(rx + 8);
    f32x4 s3 = *(const f32x4*)(rb + 12);
    f32x4 x3 = *(const f32x4*)(rx + 12);
    float4 r0, r1, r2, r3;
#pragma unroll
    for (int k4 = 0; k4 < 4; ++k4) {
      f32x4 Sq = (k4 == 0) ? s0 : (k4 == 1) ? s1 : (k4 == 2) ? s2 : s3;
      f32x4 Xq = (k4 == 0) ? x0 : (k4 == 1) ? x1 : (k4 == 2) ? x2 : x3;
      float4 rv;
#pragma unroll
      for (int e = 0; e < 4; ++e) {
        float t1  = KB + Xq[e];                           // off critical path
        float spk = KB + Sq[e];                           // off critical path
        float pu = dpp_mov<0x138, 0xf, true>(0.f, dcur);  // D[i-1], wave_shr:1
        pu = l0c ? dcur : pu;                             // lanes 0/32 -> self
        float mn = fminf(dcur, pu);
        float u  = fmaf(nw, mn, t1);                      // u = KB + Sx - w*mn
        float Mx = scan_max32(u);                         // fused 5-op scan
        float val = spk - Mx;                             // S + prefmin(e)
        if (first && k4 == 0 && e == 0)                   // init col = cumsum
          val = Sq[0];                                    // ... which IS S
        dcur = val;
        if (e == 0) rv.x = val; else if (e == 1) rv.y = val;
        else if (e == 2) rv.z = val; else rv.w = val;
      }
      if (k4 == 0) r0 = rv; else if (k4 == 1) r1 = rv;
      else if (k4 == 2) r2 = rv; else r3 = rv;
    }
    if (store) {                      // one exec-mask region per tile
      if (l31) {
        float4 s;
        s.x = __builtin_amdgcn_sqrtf(r0.x); s.y = __builtin_amdgcn_sqrtf(r0.y);
        s.z = __builtin_amdgcn_sqrtf(r0.z); s.w = __builtin_amdgcn_sqrtf(r0.w);
        *(float4*)(op + 0) = s;
        s.x = __builtin_amdgcn_sqrtf(r1.x); s.y = __builtin_amdgcn_sqrtf(r1.y);
        s.z = __builtin_amdgcn_sqrtf(r1.z); s.w = __builtin_amdgcn_sqrtf(r1.w);
        *(float4*)(op + 4) = s;
        s.x = __builtin_amdgcn_sqrtf(r2.x); s.y = __builtin_amdgcn_sqrtf(r2.y);
        s.z = __builtin_amdgcn_sqrtf(r2.z); s.w = __builtin_amdgcn_sqrtf(r2.w);
        *(float4*)(op + 8) = s;
        s.x = __builtin_amdgcn_sqrtf(r3.x); s.y = __builtin_amdgcn_sqrtf(r3.y);
        s.z = __builtin_amdgcn_sqrtf(r3.z); s.w = __builtin_amdgcn_sqrtf(r3.w);
        *(float4*)(op + 12) = s;
      }
    }
  };

  loadA(0);
  fill(0);
  loadA(1);
  for (int t = 0; t < 32; ++t) {
    if (t + 1 < 32) fill((t & 1) ^ 1);   // consumes Aa = frag(t+1)
    if (t + 2 < 32) loadA(t + 2);
    DP(t & 1, t == 0, t >= warmT, orow + (t << 4));
  }
}

extern "C" void kernel_launch(void* const* d_in, const int* in_sizes, int n_in,
                              void* d_out, int out_size, void* d_ws, size_t ws_size,
                              hipStream_t stream) {
  const float* x     = (const float*)d_in[0];
  const float* patts = (const float*)d_in[1];
  const float* w     = (const float*)d_in[2];
  float* out = (float*)d_out;

  ushort_t* xA = (ushort_t*)d_ws;                                       // 2 MiB
  ushort_t* pB = (ushort_t*)((char*)d_ws + (size_t)B_ * T_ * 32 * 2);   // 128 KiB

  prep_x<<<(B_ * T_ + 255) / 256, 256, 0, stream>>>(x, xA);
  prep_patt<<<P_, 64, 0, stream>>>(patts, pB);
  dtw_kernel<<<B_ * (P_ / 8) * 3, 256, 0, stream>>>(xA, pB, w, out);
}